// Round 4
// baseline (1282.814 us; speedup 1.0000x reference)
//
#include <hip/hip_runtime.h>
#include <hip/hip_bf16.h>
#include <hip/hip_fp16.h>

#define N_NODES 100000
#define N_EDGES 3200000
#define DIM0 512   // IN_DIM * N_SEQ
#define DIM1 256   // HID1
#define DIM2 128   // HID2
#define DIM3 64    // END
#define NSB 98     // ceil(N_NODES / 1024)

#define HPART 16384      // histogram counters per partition (64 KB LDS)
#define NPARTS 7         // ceil(N_NODES / HPART)
#define HBLK 32          // blocks per (array, partition) job

typedef _Float16 f16x8 __attribute__((ext_vector_type(8)));
typedef float f32x4 __attribute__((ext_vector_type(4)));

// ---------------- CSR build ----------------

// LDS multipass histogram: job = (array, partition); 32 blocks per job each
// cover the edge list collectively; random atomics land in LDS, merge is
// coalesced global atomics.
__global__ __launch_bounds__(256) void k_hist_lds(const int* __restrict__ src,
                                                  const int* __restrict__ dst,
                                                  int* __restrict__ cnt_out,
                                                  int* __restrict__ cnt_in) {
    __shared__ int h[HPART];
    int job = blockIdx.x / HBLK;       // 0 .. 2*NPARTS-1
    int sub = blockIdx.x % HBLK;
    int arr = job / NPARTS;            // 0 = out-degree (src), 1 = in-degree (dst)
    int part = job % NPARTS;
    int base = part * HPART;
    const int* __restrict__ keys = arr ? dst : src;
    int* __restrict__ cnt = arr ? cnt_in : cnt_out;

    for (int i = threadIdx.x; i < HPART; i += 256) h[i] = 0;
    __syncthreads();
    for (int e = sub * 256 + threadIdx.x; e < N_EDGES; e += HBLK * 256) {
        int k = keys[e] - base;
        if ((unsigned)k < (unsigned)HPART) atomicAdd(&h[k], 1);
    }
    __syncthreads();
    int lim = N_NODES - base; if (lim > HPART) lim = HPART;
    for (int i = threadIdx.x; i < lim; i += 256) {
        int v = h[i];
        if (v) atomicAdd(&cnt[base + i], v);
    }
}

__global__ __launch_bounds__(1024) void k_scan_a(const int* __restrict__ cnt,
                                                 int* __restrict__ excl,
                                                 int* __restrict__ bsum) {
    __shared__ int buf[1024];
    int tid = threadIdx.x;
    int i = blockIdx.x * 1024 + tid;
    int v = (i < N_NODES) ? cnt[i] : 0;
    buf[tid] = v;
    __syncthreads();
    #pragma unroll
    for (int off = 1; off < 1024; off <<= 1) {
        int t = (tid >= off) ? buf[tid - off] : 0;
        __syncthreads();
        buf[tid] += t;
        __syncthreads();
    }
    if (i < N_NODES) excl[i] = buf[tid] - v;
    if (tid == 1023) bsum[blockIdx.x] = buf[1023];
}

__global__ __launch_bounds__(128) void k_scan_b(const int* __restrict__ bsum,
                                                int* __restrict__ boff) {
    __shared__ int buf[128];
    int tid = threadIdx.x;
    int v = (tid < NSB) ? bsum[tid] : 0;
    buf[tid] = v;
    __syncthreads();
    #pragma unroll
    for (int off = 1; off < 128; off <<= 1) {
        int t = (tid >= off) ? buf[tid - off] : 0;
        __syncthreads();
        buf[tid] += t;
        __syncthreads();
    }
    if (tid < NSB) boff[tid] = buf[tid] - v;
    if (tid == 127) boff[NSB] = buf[127];
}

// row_ptr + cursor copy + degree scales, one pass
__global__ __launch_bounds__(256) void k_scan_c(const int* __restrict__ excl,
                                                const int* __restrict__ boff,
                                                const int* __restrict__ cnt_out,
                                                const int* __restrict__ cnt_in,
                                                int* __restrict__ row_ptr,
                                                int* __restrict__ cursor,
                                                float* __restrict__ s_out,
                                                float* __restrict__ s_in) {
    int i = blockIdx.x * 256 + threadIdx.x;
    if (i < N_NODES) {
        int rp = excl[i] + boff[i >> 10];
        row_ptr[i] = rp;
        cursor[i] = rp;
        int co = cnt_out[i]; if (co < 1) co = 1;
        int ci = cnt_in[i];  if (ci < 1) ci = 1;
        s_out[i] = rsqrtf((float)co);
        s_in[i]  = rsqrtf((float)ci);
    }
    if (i == 0) row_ptr[N_NODES] = boff[NSB];
}

// fused position-assign + scatter: 3.2M random atomics (was 6.4M + pos traffic)
__global__ __launch_bounds__(256) void k_scatter(const int* __restrict__ src,
                                                 const int* __restrict__ dst,
                                                 int* __restrict__ cursor,
                                                 int* __restrict__ esrc) {
    int e = blockIdx.x * 256 + threadIdx.x;
    if (e < N_EDGES) {
        int p = atomicAdd(&cursor[dst[e]], 1);
        esrc[p] = src[e];
    }
}

// ---------------- weight convert + transpose (tiny) ----------------

__global__ __launch_bounds__(256) void k_cvtW1(const float* __restrict__ W1,
                                               __half* __restrict__ W1t) {
    int idx = blockIdx.x * 256 + threadIdx.x;
    if (idx < DIM0 * DIM1) {
        int k = idx / DIM1, n = idx % DIM1;
        W1t[n * DIM0 + k] = __float2half(W1[idx]); // [256][512]
    }
}

__global__ __launch_bounds__(256) void k_cvtW2(const float* __restrict__ W2,
                                               __half* __restrict__ W2t) {
    int idx = blockIdx.x * 256 + threadIdx.x;
    if (idx < DIM1 * DIM2) {
        int k = idx / DIM2, n = idx % DIM2;
        W2t[n * DIM1 + k] = __float2half(W2[idx]); // [128][256]
    }
}

// ---- GEMM1 (MFMA fp16): y1 = fp16((feat * s_out) @ W1), tile 64 x 256(full), BK=32

__global__ __launch_bounds__(256) void k_gemm1(const float* __restrict__ feat,
                                               const float* __restrict__ s_out,
                                               const __half* __restrict__ W1t,
                                               __half* __restrict__ y) {
    __shared__ __align__(16) _Float16 As[64][40];    // 64 rows x 32k (+8 pad)
    __shared__ __align__(16) _Float16 Bs[256][40];   // 256 cols x 32k (+8 pad)
    int tid = threadIdx.x;
    int wv = tid >> 6, lane = tid & 63;
    int m16 = lane & 15, quad = lane >> 4;
    int n0 = blockIdx.x * 64;

    int srow = tid >> 2;
    int scol = (tid & 3) * 8;
    int gr = n0 + srow;
    bool avalid = gr < N_NODES;
    int grc = avalid ? gr : (N_NODES - 1);
    float ascale = avalid ? s_out[gr] : 0.0f;
    const float* aptr = feat + (size_t)grc * DIM0 + scol;
    int bn = tid >> 2;
    int bc = (tid & 3) * 8;

    f32x4 acc[4][4] = {};
    for (int k0 = 0; k0 < DIM0; k0 += 32) {
        float4 f0 = *(const float4*)(aptr + k0);
        float4 f1 = *(const float4*)(aptr + k0 + 4);
        __syncthreads();
        {
            f16x8 h;
            h[0] = (_Float16)(f0.x * ascale); h[1] = (_Float16)(f0.y * ascale);
            h[2] = (_Float16)(f0.z * ascale); h[3] = (_Float16)(f0.w * ascale);
            h[4] = (_Float16)(f1.x * ascale); h[5] = (_Float16)(f1.y * ascale);
            h[6] = (_Float16)(f1.z * ascale); h[7] = (_Float16)(f1.w * ascale);
            *(f16x8*)&As[srow][scol] = h;
        }
        #pragma unroll
        for (int p = 0; p < 4; ++p) {
            int n = p * 64 + bn;
            f16x8 v = *(const f16x8*)(W1t + (size_t)n * DIM0 + k0 + bc);
            *(f16x8*)&Bs[n][bc] = v;
        }
        __syncthreads();
        f16x8 af[4], bf[4];
        #pragma unroll
        for (int r = 0; r < 4; ++r) af[r] = *(const f16x8*)&As[r * 16 + m16][quad * 8];
        #pragma unroll
        for (int c = 0; c < 4; ++c) bf[c] = *(const f16x8*)&Bs[wv * 64 + c * 16 + m16][quad * 8];
        #pragma unroll
        for (int r = 0; r < 4; ++r)
            #pragma unroll
            for (int c = 0; c < 4; ++c)
                acc[r][c] = __builtin_amdgcn_mfma_f32_16x16x32_f16(af[r], bf[c], acc[r][c], 0, 0, 0);
    }
    #pragma unroll
    for (int r = 0; r < 4; ++r) {
        #pragma unroll
        for (int i = 0; i < 4; ++i) {
            int row = n0 + r * 16 + quad * 4 + i;
            if (row < N_NODES) {
                #pragma unroll
                for (int c = 0; c < 4; ++c) {
                    int col = wv * 64 + c * 16 + m16;
                    y[(size_t)row * DIM1 + col] = __float2half(acc[r][c][i]);
                }
            }
        }
    }
}

// ---- aggregation dim=256 (fp16 payload) + fused relu(x*s_in+b1)*s_out epilogue ----

__global__ __launch_bounds__(256) void k_agg256(const int* __restrict__ row_ptr,
                                                const int* __restrict__ esrc,
                                                const __half* __restrict__ y1,
                                                const float* __restrict__ s_in,
                                                const float* __restrict__ s_out,
                                                const float* __restrict__ b1,
                                                __half* __restrict__ x2) {
    int wave = threadIdx.x >> 6;
    int lane = threadIdx.x & 63;
    int n = blockIdx.x * 4 + wave;   // 25000 * 4 = 100000 exact
    int beg = row_ptr[n], end = row_ptr[n + 1];
    const uint2* ybase = (const uint2*)y1;
    float4 acc = make_float4(0.f, 0.f, 0.f, 0.f);
    int i = beg;
    for (; i + 4 <= end; i += 4) {
        int s0 = esrc[i], s1 = esrc[i + 1], s2 = esrc[i + 2], s3 = esrc[i + 3];
        uint2 r0 = ybase[(size_t)s0 * 64 + lane];
        uint2 r1 = ybase[(size_t)s1 * 64 + lane];
        uint2 r2 = ybase[(size_t)s2 * 64 + lane];
        uint2 r3 = ybase[(size_t)s3 * 64 + lane];
        float2 a0 = __half22float2(*(__half2*)&r0.x), b0 = __half22float2(*(__half2*)&r0.y);
        float2 a1 = __half22float2(*(__half2*)&r1.x), b1v = __half22float2(*(__half2*)&r1.y);
        float2 a2 = __half22float2(*(__half2*)&r2.x), b2v = __half22float2(*(__half2*)&r2.y);
        float2 a3 = __half22float2(*(__half2*)&r3.x), b3v = __half22float2(*(__half2*)&r3.y);
        acc.x += a0.x + a1.x + a2.x + a3.x;
        acc.y += a0.y + a1.y + a2.y + a3.y;
        acc.z += b0.x + b1v.x + b2v.x + b3v.x;
        acc.w += b0.y + b1v.y + b2v.y + b3v.y;
    }
    for (; i < end; ++i) {
        uint2 r = ybase[(size_t)esrc[i] * 64 + lane];
        float2 a = __half22float2(*(__half2*)&r.x), b = __half22float2(*(__half2*)&r.y);
        acc.x += a.x; acc.y += a.y; acc.z += b.x; acc.w += b.y;
    }
    float si = s_in[n];
    float so = s_out[n];
    float4 bb = *(const float4*)&b1[lane * 4];
    acc.x = fmaxf(acc.x * si + bb.x, 0.f) * so;
    acc.y = fmaxf(acc.y * si + bb.y, 0.f) * so;
    acc.z = fmaxf(acc.z * si + bb.z, 0.f) * so;
    acc.w = fmaxf(acc.w * si + bb.w, 0.f) * so;
    union { uint2 u; __half2 h[2]; } cv;
    cv.h[0] = __floats2half2_rn(acc.x, acc.y);
    cv.h[1] = __floats2half2_rn(acc.z, acc.w);
    *(uint2*)&x2[(size_t)n * DIM1 + lane * 4] = cv.u;
}

// ---- GEMM2 (MFMA fp16): y2 = fp16(x2 @ W2), tile 64 x 128(full), BK=32 ----

__global__ __launch_bounds__(256) void k_gemm2(const __half* __restrict__ x2,
                                               const __half* __restrict__ W2t,
                                               __half* __restrict__ y) {
    __shared__ __align__(16) _Float16 As[64][40];
    __shared__ __align__(16) _Float16 Bs[128][40];
    int tid = threadIdx.x;
    int wv = tid >> 6, lane = tid & 63;
    int m16 = lane & 15, quad = lane >> 4;
    int n0 = blockIdx.x * 64;

    int srow = tid >> 2;
    int scol = (tid & 3) * 8;
    int gr = n0 + srow;
    int grc = (gr < N_NODES) ? gr : (N_NODES - 1);
    const __half* aptr = x2 + (size_t)grc * DIM1 + scol;
    int bn = tid >> 2;
    int bc = (tid & 3) * 8;

    f32x4 acc[4][2] = {};
    for (int k0 = 0; k0 < DIM1; k0 += 32) {
        f16x8 av = *(const f16x8*)(aptr + k0);
        __syncthreads();
        *(f16x8*)&As[srow][scol] = av;
        #pragma unroll
        for (int p = 0; p < 2; ++p) {
            int n = p * 64 + bn;
            f16x8 v = *(const f16x8*)(W2t + (size_t)n * DIM1 + k0 + bc);
            *(f16x8*)&Bs[n][bc] = v;
        }
        __syncthreads();
        f16x8 af[4], bf[2];
        #pragma unroll
        for (int r = 0; r < 4; ++r) af[r] = *(const f16x8*)&As[r * 16 + m16][quad * 8];
        #pragma unroll
        for (int c = 0; c < 2; ++c) bf[c] = *(const f16x8*)&Bs[wv * 32 + c * 16 + m16][quad * 8];
        #pragma unroll
        for (int r = 0; r < 4; ++r)
            #pragma unroll
            for (int c = 0; c < 2; ++c)
                acc[r][c] = __builtin_amdgcn_mfma_f32_16x16x32_f16(af[r], bf[c], acc[r][c], 0, 0, 0);
    }
    #pragma unroll
    for (int r = 0; r < 4; ++r) {
        #pragma unroll
        for (int i = 0; i < 4; ++i) {
            int row = n0 + r * 16 + quad * 4 + i;
            if (row < N_NODES) {
                #pragma unroll
                for (int c = 0; c < 2; ++c) {
                    int col = wv * 32 + c * 16 + m16;
                    y[(size_t)row * DIM2 + col] = __float2half(acc[r][c][i]);
                }
            }
        }
    }
}

// ---- fused aggregation dim=128 (fp16 payload) + MLP head, one wave per node ----

__global__ __launch_bounds__(256) void k_agg_head(const int* __restrict__ row_ptr,
                                                  const int* __restrict__ esrc,
                                                  const __half* __restrict__ y2,
                                                  const float* __restrict__ s_in,
                                                  const float* __restrict__ b2,
                                                  const float* __restrict__ Wo1,
                                                  const float* __restrict__ bo1,
                                                  const float* __restrict__ Wo2,
                                                  const float* __restrict__ bo2,
                                                  float* __restrict__ out) {
    __shared__ float w1s[DIM2 * DIM3];   // 32 KB
    __shared__ float w2s[DIM3];
    __shared__ float hs[4][DIM2];
    int tid = threadIdx.x;
    for (int i = tid; i < DIM2 * DIM3; i += 256) w1s[i] = Wo1[i];
    if (tid < DIM3) w2s[tid] = Wo2[tid];
    __syncthreads();

    int wave = tid >> 6, lane = tid & 63;
    int n = blockIdx.x * 4 + wave;
    int beg = row_ptr[n], end = row_ptr[n + 1];
    const unsigned* ybase = (const unsigned*)y2;
    float2 acc = make_float2(0.f, 0.f);
    int i = beg;
    for (; i + 4 <= end; i += 4) {
        unsigned r0 = ybase[(size_t)esrc[i] * 64 + lane];
        unsigned r1 = ybase[(size_t)esrc[i + 1] * 64 + lane];
        unsigned r2 = ybase[(size_t)esrc[i + 2] * 64 + lane];
        unsigned r3 = ybase[(size_t)esrc[i + 3] * 64 + lane];
        float2 f0 = __half22float2(*(__half2*)&r0);
        float2 f1 = __half22float2(*(__half2*)&r1);
        float2 f2 = __half22float2(*(__half2*)&r2);
        float2 f3 = __half22float2(*(__half2*)&r3);
        acc.x += f0.x + f1.x + f2.x + f3.x;
        acc.y += f0.y + f1.y + f2.y + f3.y;
    }
    for (; i < end; ++i) {
        unsigned r = ybase[(size_t)esrc[i] * 64 + lane];
        float2 f = __half22float2(*(__half2*)&r);
        acc.x += f.x; acc.y += f.y;
    }
    float si = s_in[n];
    float2 bv = *(const float2*)&b2[lane * 2];
    hs[wave][lane * 2 + 0] = acc.x * si + bv.x;
    hs[wave][lane * 2 + 1] = acc.y * si + bv.y;
    __syncthreads();

    float t = bo1[lane];
    #pragma unroll 8
    for (int k = 0; k < DIM2; ++k) t += hs[wave][k] * w1s[k * DIM3 + lane];
    t = fmaxf(t, 0.f);
    float p = t * w2s[lane];
    #pragma unroll
    for (int off = 32; off > 0; off >>= 1) p += __shfl_down(p, off);
    if (lane == 0) out[n] = p + bo2[0];
}

// ---------------- launch ----------------

extern "C" void kernel_launch(void* const* d_in, const int* in_sizes, int n_in,
                              void* d_out, int out_size, void* d_ws, size_t ws_size,
                              hipStream_t stream) {
    const float* feat = (const float*)d_in[0];
    const int*   src  = (const int*)d_in[1];
    const int*   dst  = (const int*)d_in[2];
    const float* W1   = (const float*)d_in[3];
    const float* b1   = (const float*)d_in[4];
    const float* W2   = (const float*)d_in[5];
    const float* b2   = (const float*)d_in[6];
    const float* Wo1  = (const float*)d_in[7];
    const float* bo1  = (const float*)d_in[8];
    const float* Wo2  = (const float*)d_in[9];
    const float* bo2  = (const float*)d_in[10];
    float* out = (float*)d_out;

    char* ws = (char*)d_ws;
    size_t off = 0;
    auto alloc = [&](size_t bytes) -> char* {
        char* p = ws + off;
        off = (off + bytes + 255) & ~(size_t)255;
        return p;
    };
    int*    cnt_out = (int*)alloc(N_NODES * 4);
    int*    cnt_in  = (int*)alloc(N_NODES * 4);
    int*    row_ptr = (int*)alloc((N_NODES + 1) * 4);
    int*    cursor  = (int*)alloc(N_NODES * 4);
    int*    excl    = (int*)alloc(N_NODES * 4);
    int*    bsum    = (int*)alloc((NSB + 1) * 4);
    int*    boff    = (int*)alloc((NSB + 1) * 4);
    int*    esrc    = (int*)alloc((size_t)N_EDGES * 4);
    float*  s_out   = (float*)alloc(N_NODES * 4);
    float*  s_in    = (float*)alloc(N_NODES * 4);
    __half* W1t     = (__half*)alloc((size_t)DIM0 * DIM1 * 2);
    __half* W2t     = (__half*)alloc((size_t)DIM1 * DIM2 * 2);
    __half* y1h     = (__half*)alloc((size_t)N_NODES * DIM1 * 2);
    __half* x2h     = (__half*)alloc((size_t)N_NODES * DIM1 * 2);
    __half* y2h     = (__half*)alloc((size_t)N_NODES * DIM2 * 2);

    hipMemsetAsync(cnt_out, 0, N_NODES * 4, stream);
    hipMemsetAsync(cnt_in, 0, N_NODES * 4, stream);

    k_hist_lds<<<2 * NPARTS * HBLK, 256, 0, stream>>>(src, dst, cnt_out, cnt_in);
    k_scan_a<<<NSB, 1024, 0, stream>>>(cnt_in, excl, bsum);
    k_scan_b<<<1, 128, 0, stream>>>(bsum, boff);
    k_scan_c<<<(N_NODES + 255) / 256, 256, 0, stream>>>(excl, boff, cnt_out, cnt_in,
                                                        row_ptr, cursor, s_out, s_in);
    k_scatter<<<(N_EDGES + 255) / 256, 256, 0, stream>>>(src, dst, cursor, esrc);

    k_cvtW1<<<(DIM0 * DIM1 + 255) / 256, 256, 0, stream>>>(W1, W1t);
    k_cvtW2<<<(DIM1 * DIM2 + 255) / 256, 256, 0, stream>>>(W2, W2t);

    int nblk = (N_NODES + 63) / 64;
    k_gemm1<<<nblk, 256, 0, stream>>>(feat, s_out, W1t, y1h);
    k_agg256<<<N_NODES / 4, 256, 0, stream>>>(row_ptr, esrc, y1h, s_in, s_out, b1, x2h);
    k_gemm2<<<nblk, 256, 0, stream>>>(x2h, W2t, y2h);
    k_agg_head<<<N_NODES / 4, 256, 0, stream>>>(row_ptr, esrc, y2h, s_in, b2,
                                                Wo1, bo1, Wo2, bo2, out);
}

// Round 5
// 1166.222 us; speedup vs baseline: 1.1000x; 1.1000x over previous
//
#include <hip/hip_runtime.h>
#include <hip/hip_bf16.h>
#include <hip/hip_fp16.h>

#define N_NODES 100000
#define N_EDGES 3200000
#define DIM0 512   // IN_DIM * N_SEQ
#define DIM1 256   // HID1
#define DIM2 128   // HID2
#define DIM3 64    // END
#define NSB 98     // ceil(N_NODES / 1024)

#define HPART 16384          // nodes per partition
#define HPAIR 8192           // packed u32 pairs per partition
#define NP 7                 // ceil(N_NODES / HPART)
#define NSL 32               // edge slices
#define SLC (N_EDGES / NSL)  // 100000 edges per slice

typedef _Float16 f16x8 __attribute__((ext_vector_type(8)));
typedef float f32x4 __attribute__((ext_vector_type(4)));

// ---------------- CSR build (zero global atomics) ----------------

// Block-private partitioned histogram. hp layout:
// [arr(2)][part(NP)][slice(NSL)][HPAIR] packed u32 (lo=even node, hi=odd node)
__global__ __launch_bounds__(256) void k_hist_priv(const int* __restrict__ src,
                                                   const int* __restrict__ dst,
                                                   unsigned* __restrict__ hp) {
    __shared__ unsigned h32[HPAIR];   // 32 KB
    int blk = blockIdx.x, part = blockIdx.y, arr = blockIdx.z;
    const int* __restrict__ keys = arr ? dst : src;
    int base = part * HPART;
    for (int i = threadIdx.x; i < HPAIR; i += 256) h32[i] = 0;
    __syncthreads();
    int e0 = blk * SLC, e1 = e0 + SLC;
    for (int e = e0 + threadIdx.x; e < e1; e += 256) {
        int k = keys[e] - base;
        if ((unsigned)k < (unsigned)HPART)
            atomicAdd(&h32[k >> 1], 1u << ((k & 1) * 16));
    }
    __syncthreads();
    unsigned* out = hp + ((size_t)(arr * NP + part) * NSL + blk) * HPAIR;
    for (int i = threadIdx.x; i < HPAIR; i += 256) out[i] = h32[i];
}

// Sum 32 private counts per node -> cnt arrays; for dst (arr=1) convert the
// private counts IN-PLACE to per-slice exclusive prefixes (scatter bases).
__global__ __launch_bounds__(256) void k_reduce(unsigned* __restrict__ hp,
                                                int* __restrict__ cnt_out,
                                                int* __restrict__ cnt_in) {
    int idx = blockIdx.x * 256 + threadIdx.x;     // over 2*NP*HPAIR = 114688
    if (idx >= 2 * NP * HPAIR) return;
    int arr = idx / (NP * HPAIR);
    int rem = idx % (NP * HPAIR);
    int part = rem / HPAIR;
    int j = rem % HPAIR;
    unsigned* p = hp + ((size_t)(arr * NP + part) * NSL) * HPAIR + j;
    unsigned lo = 0, hi = 0;
    #pragma unroll 8
    for (int b = 0; b < NSL; ++b) {
        unsigned v = p[(size_t)b * HPAIR];
        if (arr == 1) p[(size_t)b * HPAIR] = (lo & 0xffffu) | (hi << 16);
        lo += v & 0xffffu;
        hi += v >> 16;
    }
    int node0 = part * HPART + 2 * j;
    int* cnt = arr ? cnt_in : cnt_out;
    if (node0 < N_NODES) cnt[node0] = (int)lo;
    if (node0 + 1 < N_NODES) cnt[node0 + 1] = (int)hi;
}

__global__ __launch_bounds__(1024) void k_scan_a(const int* __restrict__ cnt,
                                                 int* __restrict__ excl,
                                                 int* __restrict__ bsum) {
    __shared__ int buf[1024];
    int tid = threadIdx.x;
    int i = blockIdx.x * 1024 + tid;
    int v = (i < N_NODES) ? cnt[i] : 0;
    buf[tid] = v;
    __syncthreads();
    #pragma unroll
    for (int off = 1; off < 1024; off <<= 1) {
        int t = (tid >= off) ? buf[tid - off] : 0;
        __syncthreads();
        buf[tid] += t;
        __syncthreads();
    }
    if (i < N_NODES) excl[i] = buf[tid] - v;
    if (tid == 1023) bsum[blockIdx.x] = buf[1023];
}

__global__ __launch_bounds__(128) void k_scan_b(const int* __restrict__ bsum,
                                                int* __restrict__ boff) {
    __shared__ int buf[128];
    int tid = threadIdx.x;
    int v = (tid < NSB) ? bsum[tid] : 0;
    buf[tid] = v;
    __syncthreads();
    #pragma unroll
    for (int off = 1; off < 128; off <<= 1) {
        int t = (tid >= off) ? buf[tid - off] : 0;
        __syncthreads();
        buf[tid] += t;
        __syncthreads();
    }
    if (tid < NSB) boff[tid] = buf[tid] - v;
    if (tid == 127) boff[NSB] = buf[127];
}

// row_ptr + degree scales, one pass
__global__ __launch_bounds__(256) void k_scan_c(const int* __restrict__ excl,
                                                const int* __restrict__ boff,
                                                const int* __restrict__ cnt_out,
                                                const int* __restrict__ cnt_in,
                                                int* __restrict__ row_ptr,
                                                float* __restrict__ s_out,
                                                float* __restrict__ s_in) {
    int i = blockIdx.x * 256 + threadIdx.x;
    if (i < N_NODES) {
        row_ptr[i] = excl[i] + boff[i >> 10];
        int co = cnt_out[i]; if (co < 1) co = 1;
        int ci = cnt_in[i];  if (ci < 1) ci = 1;
        s_out[i] = rsqrtf((float)co);
        s_in[i]  = rsqrtf((float)ci);
    }
    if (i == 0) row_ptr[N_NODES] = boff[NSB];
}

// Atomic-free (global) scatter: block (slice, part) claims positions via LDS.
__global__ __launch_bounds__(256) void k_scatter_nr(const int* __restrict__ src,
                                                    const int* __restrict__ dst,
                                                    const int* __restrict__ row_ptr,
                                                    const unsigned* __restrict__ hp,
                                                    int* __restrict__ esrc) {
    __shared__ int base_s[HPART];   // 64 KB
    int blk = blockIdx.x, part = blockIdx.y;
    int pbase = part * HPART;
    const unsigned* off_p = hp + ((size_t)(1 * NP + part) * NSL + blk) * HPAIR;
    for (int k = threadIdx.x; k < HPART; k += 256) {
        int node = pbase + k;
        int rp = (node < N_NODES) ? row_ptr[node] : 0;
        unsigned w = off_p[k >> 1];
        unsigned off = (k & 1) ? (w >> 16) : (w & 0xffffu);
        base_s[k] = rp + (int)off;
    }
    __syncthreads();
    int e0 = blk * SLC, e1 = e0 + SLC;
    for (int e = e0 + threadIdx.x; e < e1; e += 256) {
        int d = dst[e];
        int k = d - pbase;
        if ((unsigned)k < (unsigned)HPART) {
            int p = atomicAdd(&base_s[k], 1);   // LDS atomic only
            esrc[p] = src[e];
        }
    }
}

// ---------------- weight convert + transpose (tiny) ----------------

__global__ __launch_bounds__(256) void k_cvtW1(const float* __restrict__ W1,
                                               __half* __restrict__ W1t) {
    int idx = blockIdx.x * 256 + threadIdx.x;
    if (idx < DIM0 * DIM1) {
        int k = idx / DIM1, n = idx % DIM1;
        W1t[n * DIM0 + k] = __float2half(W1[idx]); // [256][512]
    }
}

__global__ __launch_bounds__(256) void k_cvtW2(const float* __restrict__ W2,
                                               __half* __restrict__ W2t) {
    int idx = blockIdx.x * 256 + threadIdx.x;
    if (idx < DIM1 * DIM2) {
        int k = idx / DIM2, n = idx % DIM2;
        W2t[n * DIM1 + k] = __float2half(W2[idx]); // [128][256]
    }
}

// ---- GEMM1 (MFMA fp16): y1 = fp16((feat * s_out) @ W1), tile 64 x 256(full), BK=32

__global__ __launch_bounds__(256) void k_gemm1(const float* __restrict__ feat,
                                               const float* __restrict__ s_out,
                                               const __half* __restrict__ W1t,
                                               __half* __restrict__ y) {
    __shared__ __align__(16) _Float16 As[64][40];    // 64 rows x 32k (+8 pad)
    __shared__ __align__(16) _Float16 Bs[256][40];   // 256 cols x 32k (+8 pad)
    int tid = threadIdx.x;
    int wv = tid >> 6, lane = tid & 63;
    int m16 = lane & 15, quad = lane >> 4;
    int n0 = blockIdx.x * 64;

    int srow = tid >> 2;
    int scol = (tid & 3) * 8;
    int gr = n0 + srow;
    bool avalid = gr < N_NODES;
    int grc = avalid ? gr : (N_NODES - 1);
    float ascale = avalid ? s_out[gr] : 0.0f;
    const float* aptr = feat + (size_t)grc * DIM0 + scol;
    int bn = tid >> 2;
    int bc = (tid & 3) * 8;

    f32x4 acc[4][4] = {};
    for (int k0 = 0; k0 < DIM0; k0 += 32) {
        float4 f0 = *(const float4*)(aptr + k0);
        float4 f1 = *(const float4*)(aptr + k0 + 4);
        __syncthreads();
        {
            f16x8 h;
            h[0] = (_Float16)(f0.x * ascale); h[1] = (_Float16)(f0.y * ascale);
            h[2] = (_Float16)(f0.z * ascale); h[3] = (_Float16)(f0.w * ascale);
            h[4] = (_Float16)(f1.x * ascale); h[5] = (_Float16)(f1.y * ascale);
            h[6] = (_Float16)(f1.z * ascale); h[7] = (_Float16)(f1.w * ascale);
            *(f16x8*)&As[srow][scol] = h;
        }
        #pragma unroll
        for (int p = 0; p < 4; ++p) {
            int n = p * 64 + bn;
            f16x8 v = *(const f16x8*)(W1t + (size_t)n * DIM0 + k0 + bc);
            *(f16x8*)&Bs[n][bc] = v;
        }
        __syncthreads();
        f16x8 af[4], bf[4];
        #pragma unroll
        for (int r = 0; r < 4; ++r) af[r] = *(const f16x8*)&As[r * 16 + m16][quad * 8];
        #pragma unroll
        for (int c = 0; c < 4; ++c) bf[c] = *(const f16x8*)&Bs[wv * 64 + c * 16 + m16][quad * 8];
        #pragma unroll
        for (int r = 0; r < 4; ++r)
            #pragma unroll
            for (int c = 0; c < 4; ++c)
                acc[r][c] = __builtin_amdgcn_mfma_f32_16x16x32_f16(af[r], bf[c], acc[r][c], 0, 0, 0);
    }
    #pragma unroll
    for (int r = 0; r < 4; ++r) {
        #pragma unroll
        for (int i = 0; i < 4; ++i) {
            int row = n0 + r * 16 + quad * 4 + i;
            if (row < N_NODES) {
                #pragma unroll
                for (int c = 0; c < 4; ++c) {
                    int col = wv * 64 + c * 16 + m16;
                    y[(size_t)row * DIM1 + col] = __float2half(acc[r][c][i]);
                }
            }
        }
    }
}

// ---- aggregation dim=256 (fp16 payload) + fused relu(x*s_in+b1)*s_out epilogue ----

__global__ __launch_bounds__(256) void k_agg256(const int* __restrict__ row_ptr,
                                                const int* __restrict__ esrc,
                                                const __half* __restrict__ y1,
                                                const float* __restrict__ s_in,
                                                const float* __restrict__ s_out,
                                                const float* __restrict__ b1,
                                                __half* __restrict__ x2) {
    int wave = threadIdx.x >> 6;
    int lane = threadIdx.x & 63;
    int n = blockIdx.x * 4 + wave;   // 25000 * 4 = 100000 exact
    int beg = row_ptr[n], end = row_ptr[n + 1];
    const uint2* ybase = (const uint2*)y1;
    float4 acc = make_float4(0.f, 0.f, 0.f, 0.f);
    int i = beg;
    for (; i + 4 <= end; i += 4) {
        int s0 = esrc[i], s1 = esrc[i + 1], s2 = esrc[i + 2], s3 = esrc[i + 3];
        uint2 r0 = ybase[(size_t)s0 * 64 + lane];
        uint2 r1 = ybase[(size_t)s1 * 64 + lane];
        uint2 r2 = ybase[(size_t)s2 * 64 + lane];
        uint2 r3 = ybase[(size_t)s3 * 64 + lane];
        float2 a0 = __half22float2(*(__half2*)&r0.x), b0 = __half22float2(*(__half2*)&r0.y);
        float2 a1 = __half22float2(*(__half2*)&r1.x), b1v = __half22float2(*(__half2*)&r1.y);
        float2 a2 = __half22float2(*(__half2*)&r2.x), b2v = __half22float2(*(__half2*)&r2.y);
        float2 a3 = __half22float2(*(__half2*)&r3.x), b3v = __half22float2(*(__half2*)&r3.y);
        acc.x += a0.x + a1.x + a2.x + a3.x;
        acc.y += a0.y + a1.y + a2.y + a3.y;
        acc.z += b0.x + b1v.x + b2v.x + b3v.x;
        acc.w += b0.y + b1v.y + b2v.y + b3v.y;
    }
    for (; i < end; ++i) {
        uint2 r = ybase[(size_t)esrc[i] * 64 + lane];
        float2 a = __half22float2(*(__half2*)&r.x), b = __half22float2(*(__half2*)&r.y);
        acc.x += a.x; acc.y += a.y; acc.z += b.x; acc.w += b.y;
    }
    float si = s_in[n];
    float so = s_out[n];
    float4 bb = *(const float4*)&b1[lane * 4];
    acc.x = fmaxf(acc.x * si + bb.x, 0.f) * so;
    acc.y = fmaxf(acc.y * si + bb.y, 0.f) * so;
    acc.z = fmaxf(acc.z * si + bb.z, 0.f) * so;
    acc.w = fmaxf(acc.w * si + bb.w, 0.f) * so;
    union { uint2 u; __half2 h[2]; } cv;
    cv.h[0] = __floats2half2_rn(acc.x, acc.y);
    cv.h[1] = __floats2half2_rn(acc.z, acc.w);
    *(uint2*)&x2[(size_t)n * DIM1 + lane * 4] = cv.u;
}

// ---- GEMM2 (MFMA fp16): y2 = fp16(x2 @ W2), tile 64 x 128(full), BK=32 ----

__global__ __launch_bounds__(256) void k_gemm2(const __half* __restrict__ x2,
                                               const __half* __restrict__ W2t,
                                               __half* __restrict__ y) {
    __shared__ __align__(16) _Float16 As[64][40];
    __shared__ __align__(16) _Float16 Bs[128][40];
    int tid = threadIdx.x;
    int wv = tid >> 6, lane = tid & 63;
    int m16 = lane & 15, quad = lane >> 4;
    int n0 = blockIdx.x * 64;

    int srow = tid >> 2;
    int scol = (tid & 3) * 8;
    int gr = n0 + srow;
    int grc = (gr < N_NODES) ? gr : (N_NODES - 1);
    const __half* aptr = x2 + (size_t)grc * DIM1 + scol;
    int bn = tid >> 2;
    int bc = (tid & 3) * 8;

    f32x4 acc[4][2] = {};
    for (int k0 = 0; k0 < DIM1; k0 += 32) {
        f16x8 av = *(const f16x8*)(aptr + k0);
        __syncthreads();
        *(f16x8*)&As[srow][scol] = av;
        #pragma unroll
        for (int p = 0; p < 2; ++p) {
            int n = p * 64 + bn;
            f16x8 v = *(const f16x8*)(W2t + (size_t)n * DIM1 + k0 + bc);
            *(f16x8*)&Bs[n][bc] = v;
        }
        __syncthreads();
        f16x8 af[4], bf[2];
        #pragma unroll
        for (int r = 0; r < 4; ++r) af[r] = *(const f16x8*)&As[r * 16 + m16][quad * 8];
        #pragma unroll
        for (int c = 0; c < 2; ++c) bf[c] = *(const f16x8*)&Bs[wv * 32 + c * 16 + m16][quad * 8];
        #pragma unroll
        for (int r = 0; r < 4; ++r)
            #pragma unroll
            for (int c = 0; c < 2; ++c)
                acc[r][c] = __builtin_amdgcn_mfma_f32_16x16x32_f16(af[r], bf[c], acc[r][c], 0, 0, 0);
    }
    #pragma unroll
    for (int r = 0; r < 4; ++r) {
        #pragma unroll
        for (int i = 0; i < 4; ++i) {
            int row = n0 + r * 16 + quad * 4 + i;
            if (row < N_NODES) {
                #pragma unroll
                for (int c = 0; c < 2; ++c) {
                    int col = wv * 32 + c * 16 + m16;
                    y[(size_t)row * DIM2 + col] = __float2half(acc[r][c][i]);
                }
            }
        }
    }
}

// ---- fused aggregation dim=128 + MLP head; Wo1 in LDS as half2 (occupancy) ----

__global__ __launch_bounds__(256) void k_agg_head(const int* __restrict__ row_ptr,
                                                  const int* __restrict__ esrc,
                                                  const __half* __restrict__ y2,
                                                  const float* __restrict__ s_in,
                                                  const float* __restrict__ b2,
                                                  const float* __restrict__ Wo1,
                                                  const float* __restrict__ bo1,
                                                  const float* __restrict__ Wo2,
                                                  const float* __restrict__ bo2,
                                                  float* __restrict__ out) {
    __shared__ __half2 w1p[DIM2 / 2][DIM3];   // 16 KB: pairs (k=2m, 2m+1) per col
    __shared__ float w2s[DIM3];
    __shared__ float hs[4][DIM2];
    int tid = threadIdx.x;
    for (int i = tid; i < (DIM2 / 2) * DIM3; i += 256) {
        int m = i >> 6, l = i & 63;
        w1p[m][l] = __floats2half2_rn(Wo1[(2 * m) * DIM3 + l], Wo1[(2 * m + 1) * DIM3 + l]);
    }
    if (tid < DIM3) w2s[tid] = Wo2[tid];
    __syncthreads();

    int wave = tid >> 6, lane = tid & 63;
    int n = blockIdx.x * 4 + wave;
    int beg = row_ptr[n], end = row_ptr[n + 1];
    const unsigned* ybase = (const unsigned*)y2;
    float2 acc = make_float2(0.f, 0.f);
    int i = beg;
    for (; i + 4 <= end; i += 4) {
        unsigned r0 = ybase[(size_t)esrc[i] * 64 + lane];
        unsigned r1 = ybase[(size_t)esrc[i + 1] * 64 + lane];
        unsigned r2 = ybase[(size_t)esrc[i + 2] * 64 + lane];
        unsigned r3 = ybase[(size_t)esrc[i + 3] * 64 + lane];
        float2 f0 = __half22float2(*(__half2*)&r0);
        float2 f1 = __half22float2(*(__half2*)&r1);
        float2 f2 = __half22float2(*(__half2*)&r2);
        float2 f3 = __half22float2(*(__half2*)&r3);
        acc.x += f0.x + f1.x + f2.x + f3.x;
        acc.y += f0.y + f1.y + f2.y + f3.y;
    }
    for (; i < end; ++i) {
        unsigned r = ybase[(size_t)esrc[i] * 64 + lane];
        float2 f = __half22float2(*(__half2*)&r);
        acc.x += f.x; acc.y += f.y;
    }
    float si = s_in[n];
    float2 bv = *(const float2*)&b2[lane * 2];
    hs[wave][lane * 2 + 0] = acc.x * si + bv.x;
    hs[wave][lane * 2 + 1] = acc.y * si + bv.y;
    __syncthreads();

    float t = bo1[lane];
    #pragma unroll 8
    for (int m = 0; m < DIM2 / 2; ++m) {
        float2 h2 = *(const float2*)&hs[wave][2 * m];
        float2 wf = __half22float2(w1p[m][lane]);
        t += h2.x * wf.x + h2.y * wf.y;
    }
    t = fmaxf(t, 0.f);
    float p = t * w2s[lane];
    #pragma unroll
    for (int off = 32; off > 0; off >>= 1) p += __shfl_down(p, off);
    if (lane == 0) out[n] = p + bo2[0];
}

// ---------------- launch ----------------

extern "C" void kernel_launch(void* const* d_in, const int* in_sizes, int n_in,
                              void* d_out, int out_size, void* d_ws, size_t ws_size,
                              hipStream_t stream) {
    const float* feat = (const float*)d_in[0];
    const int*   src  = (const int*)d_in[1];
    const int*   dst  = (const int*)d_in[2];
    const float* W1   = (const float*)d_in[3];
    const float* b1   = (const float*)d_in[4];
    const float* W2   = (const float*)d_in[5];
    const float* b2   = (const float*)d_in[6];
    const float* Wo1  = (const float*)d_in[7];
    const float* bo1  = (const float*)d_in[8];
    const float* Wo2  = (const float*)d_in[9];
    const float* bo2  = (const float*)d_in[10];
    float* out = (float*)d_out;

    char* ws = (char*)d_ws;
    size_t off = 0;
    auto alloc = [&](size_t bytes) -> char* {
        char* p = ws + off;
        off = (off + bytes + 255) & ~(size_t)255;
        return p;
    };
    int*      cnt_out = (int*)alloc(N_NODES * 4);
    int*      cnt_in  = (int*)alloc(N_NODES * 4);
    int*      row_ptr = (int*)alloc((N_NODES + 1) * 4);
    int*      excl    = (int*)alloc(N_NODES * 4);
    int*      bsum    = (int*)alloc((NSB + 1) * 4);
    int*      boff    = (int*)alloc((NSB + 1) * 4);
    int*      esrc    = (int*)alloc((size_t)N_EDGES * 4);
    unsigned* histp   = (unsigned*)alloc((size_t)2 * NP * NSL * HPAIR * 4); // 14.7 MB
    float*    s_out   = (float*)alloc(N_NODES * 4);
    float*    s_in    = (float*)alloc(N_NODES * 4);
    __half*   W1t     = (__half*)alloc((size_t)DIM0 * DIM1 * 2);
    __half*   W2t     = (__half*)alloc((size_t)DIM1 * DIM2 * 2);
    __half*   y1h     = (__half*)alloc((size_t)N_NODES * DIM1 * 2);
    __half*   x2h     = (__half*)alloc((size_t)N_NODES * DIM1 * 2);
    __half*   y2h     = (__half*)alloc((size_t)N_NODES * DIM2 * 2);

    k_hist_priv<<<dim3(NSL, NP, 2), 256, 0, stream>>>(src, dst, histp);
    k_reduce<<<(2 * NP * HPAIR + 255) / 256, 256, 0, stream>>>(histp, cnt_out, cnt_in);
    k_scan_a<<<NSB, 1024, 0, stream>>>(cnt_in, excl, bsum);
    k_scan_b<<<1, 128, 0, stream>>>(bsum, boff);
    k_scan_c<<<(N_NODES + 255) / 256, 256, 0, stream>>>(excl, boff, cnt_out, cnt_in,
                                                        row_ptr, s_out, s_in);
    k_scatter_nr<<<dim3(NSL, NP), 256, 0, stream>>>(src, dst, row_ptr, histp, esrc);

    k_cvtW1<<<(DIM0 * DIM1 + 255) / 256, 256, 0, stream>>>(W1, W1t);
    k_cvtW2<<<(DIM1 * DIM2 + 255) / 256, 256, 0, stream>>>(W2, W2t);

    int nblk = (N_NODES + 63) / 64;
    k_gemm1<<<nblk, 256, 0, stream>>>(feat, s_out, W1t, y1h);
    k_agg256<<<N_NODES / 4, 256, 0, stream>>>(row_ptr, esrc, y1h, s_in, s_out, b1, x2h);
    k_gemm2<<<nblk, 256, 0, stream>>>(x2h, W2t, y2h);
    k_agg_head<<<N_NODES / 4, 256, 0, stream>>>(row_ptr, esrc, y2h, s_in, b2,
                                                Wo1, bo1, Wo2, bo2, out);
}

// Round 6
// 1101.204 us; speedup vs baseline: 1.1649x; 1.0590x over previous
//
#include <hip/hip_runtime.h>
#include <hip/hip_bf16.h>
#include <hip/hip_fp16.h>

#define N_NODES 100000
#define N_EDGES 3200000
#define DIM0 512   // IN_DIM * N_SEQ
#define DIM1 256   // HID1
#define DIM2 128   // HID2
#define DIM3 64    // END
#define NSB 98     // ceil(N_NODES / 1024)

#define HPART 16384          // nodes per partition
#define HPAIR 8192           // packed u32 pairs per partition
#define NP 7                 // ceil(N_NODES / HPART)
#define NSL 32               // edge slices
#define SLC (N_EDGES / NSL)  // 100000 edges per slice

typedef _Float16 f16x8 __attribute__((ext_vector_type(8)));
typedef float f32x4 __attribute__((ext_vector_type(4)));

// ---------------- CSR build (zero global atomics) ----------------

__global__ __launch_bounds__(256) void k_hist_priv(const int* __restrict__ src,
                                                   const int* __restrict__ dst,
                                                   unsigned* __restrict__ hp) {
    __shared__ unsigned h32[HPAIR];   // 32 KB
    int blk = blockIdx.x, part = blockIdx.y, arr = blockIdx.z;
    const int* __restrict__ keys = arr ? dst : src;
    int base = part * HPART;
    for (int i = threadIdx.x; i < HPAIR; i += 256) h32[i] = 0;
    __syncthreads();
    int e0 = blk * SLC, e1 = e0 + SLC;
    for (int e = e0 + threadIdx.x; e < e1; e += 256) {
        int k = keys[e] - base;
        if ((unsigned)k < (unsigned)HPART)
            atomicAdd(&h32[k >> 1], 1u << ((k & 1) * 16));
    }
    __syncthreads();
    unsigned* out = hp + ((size_t)(arr * NP + part) * NSL + blk) * HPAIR;
    for (int i = threadIdx.x; i < HPAIR; i += 256) out[i] = h32[i];
}

__global__ __launch_bounds__(256) void k_reduce(unsigned* __restrict__ hp,
                                                int* __restrict__ cnt_out,
                                                int* __restrict__ cnt_in) {
    int idx = blockIdx.x * 256 + threadIdx.x;     // over 2*NP*HPAIR
    if (idx >= 2 * NP * HPAIR) return;
    int arr = idx / (NP * HPAIR);
    int rem = idx % (NP * HPAIR);
    int part = rem / HPAIR;
    int j = rem % HPAIR;
    unsigned* p = hp + ((size_t)(arr * NP + part) * NSL) * HPAIR + j;
    unsigned lo = 0, hi = 0;
    #pragma unroll 8
    for (int b = 0; b < NSL; ++b) {
        unsigned v = p[(size_t)b * HPAIR];
        if (arr == 1) p[(size_t)b * HPAIR] = (lo & 0xffffu) | (hi << 16);
        lo += v & 0xffffu;
        hi += v >> 16;
    }
    int node0 = part * HPART + 2 * j;
    int* cnt = arr ? cnt_in : cnt_out;
    if (node0 < N_NODES) cnt[node0] = (int)lo;
    if (node0 + 1 < N_NODES) cnt[node0 + 1] = (int)hi;
}

__global__ __launch_bounds__(1024) void k_scan_a(const int* __restrict__ cnt,
                                                 int* __restrict__ excl,
                                                 int* __restrict__ bsum) {
    __shared__ int buf[1024];
    int tid = threadIdx.x;
    int i = blockIdx.x * 1024 + tid;
    int v = (i < N_NODES) ? cnt[i] : 0;
    buf[tid] = v;
    __syncthreads();
    #pragma unroll
    for (int off = 1; off < 1024; off <<= 1) {
        int t = (tid >= off) ? buf[tid - off] : 0;
        __syncthreads();
        buf[tid] += t;
        __syncthreads();
    }
    if (i < N_NODES) excl[i] = buf[tid] - v;
    if (tid == 1023) bsum[blockIdx.x] = buf[1023];
}

__global__ __launch_bounds__(128) void k_scan_b(const int* __restrict__ bsum,
                                                int* __restrict__ boff) {
    __shared__ int buf[128];
    int tid = threadIdx.x;
    int v = (tid < NSB) ? bsum[tid] : 0;
    buf[tid] = v;
    __syncthreads();
    #pragma unroll
    for (int off = 1; off < 128; off <<= 1) {
        int t = (tid >= off) ? buf[tid - off] : 0;
        __syncthreads();
        buf[tid] += t;
        __syncthreads();
    }
    if (tid < NSB) boff[tid] = buf[tid] - v;
    if (tid == 127) boff[NSB] = buf[127];
}

__global__ __launch_bounds__(256) void k_scan_c(const int* __restrict__ excl,
                                                const int* __restrict__ boff,
                                                const int* __restrict__ cnt_out,
                                                const int* __restrict__ cnt_in,
                                                int* __restrict__ row_ptr,
                                                float* __restrict__ s_out,
                                                float* __restrict__ s_in) {
    int i = blockIdx.x * 256 + threadIdx.x;
    if (i < N_NODES) {
        row_ptr[i] = excl[i] + boff[i >> 10];
        int co = cnt_out[i]; if (co < 1) co = 1;
        int ci = cnt_in[i];  if (ci < 1) ci = 1;
        s_out[i] = rsqrtf((float)co);
        s_in[i]  = rsqrtf((float)ci);
    }
    if (i == 0) row_ptr[N_NODES] = boff[NSB];
}

__global__ __launch_bounds__(256) void k_scatter_nr(const int* __restrict__ src,
                                                    const int* __restrict__ dst,
                                                    const int* __restrict__ row_ptr,
                                                    const unsigned* __restrict__ hp,
                                                    int* __restrict__ esrc) {
    __shared__ int base_s[HPART];   // 64 KB
    int blk = blockIdx.x, part = blockIdx.y;
    int pbase = part * HPART;
    const unsigned* off_p = hp + ((size_t)(1 * NP + part) * NSL + blk) * HPAIR;
    for (int k = threadIdx.x; k < HPART; k += 256) {
        int node = pbase + k;
        int rp = (node < N_NODES) ? row_ptr[node] : 0;
        unsigned w = off_p[k >> 1];
        unsigned off = (k & 1) ? (w >> 16) : (w & 0xffffu);
        base_s[k] = rp + (int)off;
    }
    __syncthreads();
    int e0 = blk * SLC, e1 = e0 + SLC;
    for (int e = e0 + threadIdx.x; e < e1; e += 256) {
        int d = dst[e];
        int k = d - pbase;
        if ((unsigned)k < (unsigned)HPART) {
            int p = atomicAdd(&base_s[k], 1);   // LDS atomic only
            esrc[p] = src[e];
        }
    }
}

// ---------------- weight convert + transpose (one dispatch) ----------------

__global__ __launch_bounds__(256) void k_cvtW(const float* __restrict__ W1,
                                              const float* __restrict__ W2,
                                              const float* __restrict__ Wo1,
                                              __half* __restrict__ W1t,
                                              __half* __restrict__ W2t,
                                              __half* __restrict__ Wo1t) {
    int idx = blockIdx.x * 256 + threadIdx.x;
    if (idx < DIM0 * DIM1) {
        int k = idx / DIM1, n = idx % DIM1;
        W1t[n * DIM0 + k] = __float2half(W1[idx]);          // [256][512]
    } else if (idx < DIM0 * DIM1 + DIM1 * DIM2) {
        int j = idx - DIM0 * DIM1;
        int k = j / DIM2, n = j % DIM2;
        W2t[n * DIM1 + k] = __float2half(W2[j]);            // [128][256]
    } else if (idx < DIM0 * DIM1 + DIM1 * DIM2 + DIM2 * DIM3) {
        int j = idx - DIM0 * DIM1 - DIM1 * DIM2;
        int k = j / DIM3, n = j % DIM3;
        Wo1t[n * DIM2 + k] = __float2half(Wo1[j]);          // [64][128]
    }
}

// ---- GEMM1 (MFMA fp16): y1 = fp16((feat * s_out) @ W1), tile 64 x 256(full), BK=32

__global__ __launch_bounds__(256) void k_gemm1(const float* __restrict__ feat,
                                               const float* __restrict__ s_out,
                                               const __half* __restrict__ W1t,
                                               __half* __restrict__ y) {
    __shared__ __align__(16) _Float16 As[64][40];
    __shared__ __align__(16) _Float16 Bs[256][40];
    int tid = threadIdx.x;
    int wv = tid >> 6, lane = tid & 63;
    int m16 = lane & 15, quad = lane >> 4;
    int n0 = blockIdx.x * 64;

    int srow = tid >> 2;
    int scol = (tid & 3) * 8;
    int gr = n0 + srow;
    bool avalid = gr < N_NODES;
    int grc = avalid ? gr : (N_NODES - 1);
    float ascale = avalid ? s_out[gr] : 0.0f;
    const float* aptr = feat + (size_t)grc * DIM0 + scol;
    int bn = tid >> 2;
    int bc = (tid & 3) * 8;

    f32x4 acc[4][4] = {};
    for (int k0 = 0; k0 < DIM0; k0 += 32) {
        float4 f0 = *(const float4*)(aptr + k0);
        float4 f1 = *(const float4*)(aptr + k0 + 4);
        __syncthreads();
        {
            f16x8 h;
            h[0] = (_Float16)(f0.x * ascale); h[1] = (_Float16)(f0.y * ascale);
            h[2] = (_Float16)(f0.z * ascale); h[3] = (_Float16)(f0.w * ascale);
            h[4] = (_Float16)(f1.x * ascale); h[5] = (_Float16)(f1.y * ascale);
            h[6] = (_Float16)(f1.z * ascale); h[7] = (_Float16)(f1.w * ascale);
            *(f16x8*)&As[srow][scol] = h;
        }
        #pragma unroll
        for (int p = 0; p < 4; ++p) {
            int n = p * 64 + bn;
            f16x8 v = *(const f16x8*)(W1t + (size_t)n * DIM0 + k0 + bc);
            *(f16x8*)&Bs[n][bc] = v;
        }
        __syncthreads();
        f16x8 af[4], bf[4];
        #pragma unroll
        for (int r = 0; r < 4; ++r) af[r] = *(const f16x8*)&As[r * 16 + m16][quad * 8];
        #pragma unroll
        for (int c = 0; c < 4; ++c) bf[c] = *(const f16x8*)&Bs[wv * 64 + c * 16 + m16][quad * 8];
        #pragma unroll
        for (int r = 0; r < 4; ++r)
            #pragma unroll
            for (int c = 0; c < 4; ++c)
                acc[r][c] = __builtin_amdgcn_mfma_f32_16x16x32_f16(af[r], bf[c], acc[r][c], 0, 0, 0);
    }
    #pragma unroll
    for (int r = 0; r < 4; ++r) {
        #pragma unroll
        for (int i = 0; i < 4; ++i) {
            int row = n0 + r * 16 + quad * 4 + i;
            if (row < N_NODES) {
                #pragma unroll
                for (int c = 0; c < 4; ++c) {
                    int col = wv * 64 + c * 16 + m16;
                    y[(size_t)row * DIM1 + col] = __float2half(acc[r][c][i]);
                }
            }
        }
    }
}

// ---- aggregation dim=256: 2 edges per load instr (32 lanes x 16B per row) ----
// fused relu(agg*s_in + b1)*s_out epilogue -> x2 fp16

__global__ __launch_bounds__(256) void k_agg256(const int* __restrict__ row_ptr,
                                                const int* __restrict__ esrc,
                                                const __half* __restrict__ y1,
                                                const float* __restrict__ s_in,
                                                const float* __restrict__ s_out,
                                                const float* __restrict__ b1,
                                                __half* __restrict__ x2) {
    int wave = threadIdx.x >> 6;
    int lane = threadIdx.x & 63;
    int sg = lane >> 5, cl = lane & 31;          // subgroup = edge slot, cl = col chunk
    int n = blockIdx.x * 4 + wave;               // 25000 * 4 = 100000 exact
    int beg = row_ptr[n], end = row_ptr[n + 1];
    const uint4* yb = (const uint4*)y1;          // 32 uint4 per row
    float acc[8] = {};
    int cnt = end - beg;
    int end2 = end - (cnt & 1);
    for (int i = beg; i < end2; i += 2) {
        int idx = esrc[i + sg];
        uint4 v = yb[(size_t)idx * 32 + cl];
        const __half2* hh = (const __half2*)&v;
        #pragma unroll
        for (int j = 0; j < 4; ++j) {
            float2 f = __half22float2(hh[j]);
            acc[2 * j] += f.x; acc[2 * j + 1] += f.y;
        }
    }
    if ((cnt & 1) && sg == 0) {
        int idx = esrc[end2];
        uint4 v = yb[(size_t)idx * 32 + cl];
        const __half2* hh = (const __half2*)&v;
        #pragma unroll
        for (int j = 0; j < 4; ++j) {
            float2 f = __half22float2(hh[j]);
            acc[2 * j] += f.x; acc[2 * j + 1] += f.y;
        }
    }
    #pragma unroll
    for (int j = 0; j < 8; ++j) acc[j] += __shfl_xor(acc[j], 32);
    if (sg == 0) {
        float si = s_in[n], so = s_out[n];
        float4 ba = *(const float4*)&b1[cl * 8];
        float4 bb = *(const float4*)&b1[cl * 8 + 4];
        float r0 = fmaxf(acc[0] * si + ba.x, 0.f) * so;
        float r1 = fmaxf(acc[1] * si + ba.y, 0.f) * so;
        float r2 = fmaxf(acc[2] * si + ba.z, 0.f) * so;
        float r3 = fmaxf(acc[3] * si + ba.w, 0.f) * so;
        float r4 = fmaxf(acc[4] * si + bb.x, 0.f) * so;
        float r5 = fmaxf(acc[5] * si + bb.y, 0.f) * so;
        float r6 = fmaxf(acc[6] * si + bb.z, 0.f) * so;
        float r7 = fmaxf(acc[7] * si + bb.w, 0.f) * so;
        union { uint4 u; __half2 h[4]; } cv;
        cv.h[0] = __floats2half2_rn(r0, r1);
        cv.h[1] = __floats2half2_rn(r2, r3);
        cv.h[2] = __floats2half2_rn(r4, r5);
        cv.h[3] = __floats2half2_rn(r6, r7);
        ((uint4*)x2)[(size_t)n * 32 + cl] = cv.u;
    }
}

// ---- GEMM2 (MFMA fp16): y2 = fp16(x2 @ W2), tile 64 x 128(full), BK=32 ----

__global__ __launch_bounds__(256) void k_gemm2(const __half* __restrict__ x2,
                                               const __half* __restrict__ W2t,
                                               __half* __restrict__ y) {
    __shared__ __align__(16) _Float16 As[64][40];
    __shared__ __align__(16) _Float16 Bs[128][40];
    int tid = threadIdx.x;
    int wv = tid >> 6, lane = tid & 63;
    int m16 = lane & 15, quad = lane >> 4;
    int n0 = blockIdx.x * 64;

    int srow = tid >> 2;
    int scol = (tid & 3) * 8;
    int gr = n0 + srow;
    int grc = (gr < N_NODES) ? gr : (N_NODES - 1);
    const __half* aptr = x2 + (size_t)grc * DIM1 + scol;
    int bn = tid >> 2;
    int bc = (tid & 3) * 8;

    f32x4 acc[4][2] = {};
    for (int k0 = 0; k0 < DIM1; k0 += 32) {
        f16x8 av = *(const f16x8*)(aptr + k0);
        __syncthreads();
        *(f16x8*)&As[srow][scol] = av;
        #pragma unroll
        for (int p = 0; p < 2; ++p) {
            int n = p * 64 + bn;
            f16x8 v = *(const f16x8*)(W2t + (size_t)n * DIM1 + k0 + bc);
            *(f16x8*)&Bs[n][bc] = v;
        }
        __syncthreads();
        f16x8 af[4], bf[2];
        #pragma unroll
        for (int r = 0; r < 4; ++r) af[r] = *(const f16x8*)&As[r * 16 + m16][quad * 8];
        #pragma unroll
        for (int c = 0; c < 2; ++c) bf[c] = *(const f16x8*)&Bs[wv * 32 + c * 16 + m16][quad * 8];
        #pragma unroll
        for (int r = 0; r < 4; ++r)
            #pragma unroll
            for (int c = 0; c < 2; ++c)
                acc[r][c] = __builtin_amdgcn_mfma_f32_16x16x32_f16(af[r], bf[c], acc[r][c], 0, 0, 0);
    }
    #pragma unroll
    for (int r = 0; r < 4; ++r) {
        #pragma unroll
        for (int i = 0; i < 4; ++i) {
            int row = n0 + r * 16 + quad * 4 + i;
            if (row < N_NODES) {
                #pragma unroll
                for (int c = 0; c < 2; ++c) {
                    int col = wv * 32 + c * 16 + m16;
                    y[(size_t)row * DIM2 + col] = __float2half(acc[r][c][i]);
                }
            }
        }
    }
}

// ---- aggregation dim=128: 4 edges per load instr (16 lanes x 16B per row) ----
// stores fp16(agg*s_in + b2) = head input

__global__ __launch_bounds__(256) void k_agg128s(const int* __restrict__ row_ptr,
                                                 const int* __restrict__ esrc,
                                                 const __half* __restrict__ y2,
                                                 const float* __restrict__ s_in,
                                                 const float* __restrict__ b2,
                                                 __half* __restrict__ xh) {
    int wave = threadIdx.x >> 6;
    int lane = threadIdx.x & 63;
    int sg = lane >> 4, cl = lane & 15;
    int n = blockIdx.x * 4 + wave;
    int beg = row_ptr[n], end = row_ptr[n + 1];
    const uint4* yb = (const uint4*)y2;          // 16 uint4 per row
    float acc[8] = {};
    int cnt = end - beg;
    int end4 = end - (cnt & 3);
    for (int i = beg; i < end4; i += 4) {
        int idx = esrc[i + sg];
        uint4 v = yb[(size_t)idx * 16 + cl];
        const __half2* hh = (const __half2*)&v;
        #pragma unroll
        for (int j = 0; j < 4; ++j) {
            float2 f = __half22float2(hh[j]);
            acc[2 * j] += f.x; acc[2 * j + 1] += f.y;
        }
    }
    int rem = cnt & 3;
    if (sg < rem) {
        int idx = esrc[end4 + sg];
        uint4 v = yb[(size_t)idx * 16 + cl];
        const __half2* hh = (const __half2*)&v;
        #pragma unroll
        for (int j = 0; j < 4; ++j) {
            float2 f = __half22float2(hh[j]);
            acc[2 * j] += f.x; acc[2 * j + 1] += f.y;
        }
    }
    #pragma unroll
    for (int j = 0; j < 8; ++j) {
        acc[j] += __shfl_xor(acc[j], 16);
        acc[j] += __shfl_xor(acc[j], 32);
    }
    if (lane < 16) {
        float si = s_in[n];
        float4 ba = *(const float4*)&b2[cl * 8];
        float4 bb = *(const float4*)&b2[cl * 8 + 4];
        union { uint4 u; __half2 h[4]; } cv;
        cv.h[0] = __floats2half2_rn(acc[0] * si + ba.x, acc[1] * si + ba.y);
        cv.h[1] = __floats2half2_rn(acc[2] * si + ba.z, acc[3] * si + ba.w);
        cv.h[2] = __floats2half2_rn(acc[4] * si + bb.x, acc[5] * si + bb.y);
        cv.h[3] = __floats2half2_rn(acc[6] * si + bb.z, acc[7] * si + bb.w);
        ((uint4*)xh)[(size_t)n * 16 + cl] = cv.u;
    }
}

// ---- head as MFMA GEMM: out = relu(xh @ Wo1 + bo1) @ Wo2 + bo2 ----
// wave tile = 16 rows x 64 cols (full), K=128; epilogue reduces cols in-wave.

__global__ __launch_bounds__(256) void k_head(const __half* __restrict__ xh,
                                              const __half* __restrict__ Wo1t,
                                              const float* __restrict__ bo1,
                                              const float* __restrict__ Wo2,
                                              const float* __restrict__ bo2,
                                              float* __restrict__ out) {
    int tid = threadIdx.x;
    int wv = tid >> 6, lane = tid & 63;
    int m16 = lane & 15, quad = lane >> 4;
    int n0 = (blockIdx.x * 4 + wv) * 16;
    if (n0 >= N_NODES) return;
    const uint4* A = (const uint4*)xh;      // 16 uint4 per row
    const uint4* B = (const uint4*)Wo1t;    // 16 uint4 per row (n-major, [64][128])
    f32x4 acc[4] = {};
    #pragma unroll
    for (int ks = 0; ks < 4; ++ks) {
        uint4 av = A[(size_t)(n0 + m16) * 16 + ks * 4 + quad];
        f16x8 af = *(const f16x8*)&av;
        #pragma unroll
        for (int ct = 0; ct < 4; ++ct) {
            uint4 bv = B[(size_t)(ct * 16 + m16) * 16 + ks * 4 + quad];
            f16x8 bf = *(const f16x8*)&bv;
            acc[ct] = __builtin_amdgcn_mfma_f32_16x16x32_f16(af, bf, acc[ct], 0, 0, 0);
        }
    }
    float bo1v[4], wo2v[4];
    #pragma unroll
    for (int ct = 0; ct < 4; ++ct) {
        int col = ct * 16 + m16;
        bo1v[ct] = bo1[col];
        wo2v[ct] = Wo2[col];
    }
    float s[4];
    #pragma unroll
    for (int r = 0; r < 4; ++r) {
        float t = 0.f;
        #pragma unroll
        for (int ct = 0; ct < 4; ++ct)
            t += fmaxf(acc[ct][r] + bo1v[ct], 0.f) * wo2v[ct];
        s[r] = t;
    }
    #pragma unroll
    for (int off = 1; off <= 8; off <<= 1)
        #pragma unroll
        for (int r = 0; r < 4; ++r) s[r] += __shfl_xor(s[r], off);
    if (m16 == 0) {
        float bb = bo2[0];
        #pragma unroll
        for (int r = 0; r < 4; ++r) out[n0 + quad * 4 + r] = s[r] + bb;
    }
}

// ---------------- launch ----------------

extern "C" void kernel_launch(void* const* d_in, const int* in_sizes, int n_in,
                              void* d_out, int out_size, void* d_ws, size_t ws_size,
                              hipStream_t stream) {
    const float* feat = (const float*)d_in[0];
    const int*   src  = (const int*)d_in[1];
    const int*   dst  = (const int*)d_in[2];
    const float* W1   = (const float*)d_in[3];
    const float* b1   = (const float*)d_in[4];
    const float* W2   = (const float*)d_in[5];
    const float* b2   = (const float*)d_in[6];
    const float* Wo1  = (const float*)d_in[7];
    const float* bo1  = (const float*)d_in[8];
    const float* Wo2  = (const float*)d_in[9];
    const float* bo2  = (const float*)d_in[10];
    float* out = (float*)d_out;

    char* ws = (char*)d_ws;
    size_t off = 0;
    auto alloc = [&](size_t bytes) -> char* {
        char* p = ws + off;
        off = (off + bytes + 255) & ~(size_t)255;
        return p;
    };
    int*      cnt_out = (int*)alloc(N_NODES * 4);
    int*      cnt_in  = (int*)alloc(N_NODES * 4);
    int*      row_ptr = (int*)alloc((N_NODES + 1) * 4);
    int*      excl    = (int*)alloc(N_NODES * 4);
    int*      bsum    = (int*)alloc((NSB + 1) * 4);
    int*      boff    = (int*)alloc((NSB + 1) * 4);
    int*      esrc    = (int*)alloc((size_t)N_EDGES * 4);
    unsigned* histp   = (unsigned*)alloc((size_t)2 * NP * NSL * HPAIR * 4); // 14.7 MB
    float*    s_out   = (float*)alloc(N_NODES * 4);
    float*    s_in    = (float*)alloc(N_NODES * 4);
    __half*   W1t     = (__half*)alloc((size_t)DIM0 * DIM1 * 2);
    __half*   W2t     = (__half*)alloc((size_t)DIM1 * DIM2 * 2);
    __half*   Wo1t    = (__half*)alloc((size_t)DIM2 * DIM3 * 2);
    __half*   y1h     = (__half*)alloc((size_t)N_NODES * DIM1 * 2);
    __half*   x2h     = (__half*)alloc((size_t)N_NODES * DIM1 * 2);
    __half*   y2h     = (__half*)alloc((size_t)N_NODES * DIM2 * 2);
    __half*   xhh     = (__half*)alloc((size_t)N_NODES * DIM2 * 2);

    k_hist_priv<<<dim3(NSL, NP, 2), 256, 0, stream>>>(src, dst, histp);
    k_reduce<<<(2 * NP * HPAIR + 255) / 256, 256, 0, stream>>>(histp, cnt_out, cnt_in);
    k_scan_a<<<NSB, 1024, 0, stream>>>(cnt_in, excl, bsum);
    k_scan_b<<<1, 128, 0, stream>>>(bsum, boff);
    k_scan_c<<<(N_NODES + 255) / 256, 256, 0, stream>>>(excl, boff, cnt_out, cnt_in,
                                                        row_ptr, s_out, s_in);
    k_scatter_nr<<<dim3(NSL, NP), 256, 0, stream>>>(src, dst, row_ptr, histp, esrc);

    int cvt_total = DIM0 * DIM1 + DIM1 * DIM2 + DIM2 * DIM3;
    k_cvtW<<<(cvt_total + 255) / 256, 256, 0, stream>>>(W1, W2, Wo1, W1t, W2t, Wo1t);

    int nblk = (N_NODES + 63) / 64;
    k_gemm1<<<nblk, 256, 0, stream>>>(feat, s_out, W1t, y1h);
    k_agg256<<<N_NODES / 4, 256, 0, stream>>>(row_ptr, esrc, y1h, s_in, s_out, b1, x2h);
    k_gemm2<<<nblk, 256, 0, stream>>>(x2h, W2t, y2h);
    k_agg128s<<<N_NODES / 4, 256, 0, stream>>>(row_ptr, esrc, y2h, s_in, b2, xhh);
    k_head<<<(N_NODES / 16 + 3) / 4, 256, 0, stream>>>(xhh, Wo1t, bo1, Wo2, bo2, out);
}